// Round 3
// baseline (173.226 us; speedup 1.0000x reference)
//
#include <hip/hip_runtime.h>

constexpr int B = 8, H = 512, W = 512;
constexpr int PLANE = H * W;
constexpr int BSTRIDE = 2 * PLANE;
constexpr int NPIX = B * PLANE;          // 2097152
constexpr int UPN = B * 1024 * 1024;     // 8388608
constexpr float LOG2E = 1.4426950408889634f;

__device__ __forceinline__ float reluf(float v) { return v > 0.f ? v : 0.f; }
__device__ __forceinline__ float frcp(float v) { return __builtin_amdgcn_rcpf(v); }

struct AttnW {
    float wq00, wq01, wq10, wq11, bq0, bq1;
    float wk00, wk01, wk10, wk11, bk0, bk1;
    float wv00, wv01, wv10, wv11, bv0, bv1;
    float rh0, rh1, rh2, rw0, rw1, rw2;
};

__device__ __forceinline__ AttnW load_w(
    const float* wq, const float* bq, const float* wk, const float* bk,
    const float* wv, const float* bv, const float* rh, const float* rw, int i)
{
    AttnW P;
    P.wq00 = wq[4*i]; P.wq01 = wq[4*i+1]; P.wq10 = wq[4*i+2]; P.wq11 = wq[4*i+3];
    P.bq0  = bq[2*i]; P.bq1  = bq[2*i+1];
    P.wk00 = wk[4*i]; P.wk01 = wk[4*i+1]; P.wk10 = wk[4*i+2]; P.wk11 = wk[4*i+3];
    P.bk0  = bk[2*i]; P.bk1  = bk[2*i+1];
    P.wv00 = wv[4*i]; P.wv01 = wv[4*i+1]; P.wv10 = wv[4*i+2]; P.wv11 = wv[4*i+3];
    P.bv0  = bv[2*i]; P.bv1  = bv[2*i+1];
    P.rh0 = rh[3*i]; P.rh1 = rh[3*i+1]; P.rh2 = rh[3*i+2];
    P.rw0 = rw[3*i]; P.rw1 = rw[3*i+1]; P.rw2 = rw[3*i+2];
    return P;
}

// 4-px attn strip. t0/t1: relu'd 3x6 neighborhoods (per channel).
// px j uses t[r][j..j+2], center = t[1][j+1].
__device__ __forceinline__ void attn_strip(
    const float (&t0)[3][6], const float (&t1)[3][6],
    const AttnW& P, float (&o0)[4], float (&o1)[4])
{
    float kb0[3][6], kb1[3][6], v0[3][6], v1[3][6];
#pragma unroll
    for (int r = 0; r < 3; ++r)
#pragma unroll
        for (int c = 0; c < 6; ++c) {
            float u0 = t0[r][c], u1 = t1[r][c];
            kb0[r][c] = fmaf(P.wk00, u0, fmaf(P.wk01, u1, P.bk0));
            kb1[r][c] = fmaf(P.wk10, u0, fmaf(P.wk11, u1, P.bk1));
            v0[r][c]  = fmaf(P.wv00, u0, fmaf(P.wv01, u1, P.bv0));
            v1[r][c]  = fmaf(P.wv10, u0, fmaf(P.wv11, u1, P.bv1));
        }
    float rhv[3] = {P.rh0, P.rh1, P.rh2};
    float rwv[3] = {P.rw0, P.rw1, P.rw2};
#pragma unroll
    for (int px = 0; px < 4; ++px) {
        float c0 = t0[1][px + 1], c1 = t1[1][px + 1];
        float q0 = fmaf(P.wq00, c0, fmaf(P.wq01, c1, P.bq0)) * LOG2E;
        float q1 = fmaf(P.wq10, c0, fmaf(P.wq11, c1, P.bq1)) * LOG2E;
        float qh[3] = {q0 * rhv[0], q0 * rhv[1], q0 * rhv[2]};  // ch0: rh by row
        float qw[3] = {q1 * rwv[0], q1 * rwv[1], q1 * rwv[2]};  // ch1: rw by col
        float s0[9], s1[9];
#pragma unroll
        for (int r = 0; r < 3; ++r)
#pragma unroll
            for (int d = 0; d < 3; ++d) {
                s0[r*3+d] = fmaf(q0, kb0[r][px+d], qh[r]);
                s1[r*3+d] = fmaf(q1, kb1[r][px+d], qw[d]);
            }
        float m0 = fmaxf(fmaxf(fmaxf(fmaxf(s0[0],s0[1]),fmaxf(s0[2],s0[3])),
                               fmaxf(fmaxf(s0[4],s0[5]),fmaxf(s0[6],s0[7]))), s0[8]);
        float m1 = fmaxf(fmaxf(fmaxf(fmaxf(s1[0],s1[1]),fmaxf(s1[2],s1[3])),
                               fmaxf(fmaxf(s1[4],s1[5]),fmaxf(s1[6],s1[7]))), s1[8]);
        float sum0 = 0.f, acc0 = 0.f, sum1 = 0.f, acc1 = 0.f;
#pragma unroll
        for (int r = 0; r < 3; ++r)
#pragma unroll
            for (int d = 0; d < 3; ++d) {
                int t = r*3+d;
                float e0 = exp2f(s0[t] - m0);
                float e1 = exp2f(s1[t] - m1);
                sum0 += e0; acc0 = fmaf(e0, v0[r][px+d], acc0);
                sum1 += e1; acc1 = fmaf(e1, v1[r][px+d], acc1);
            }
        o0[px] = acc0 * frcp(sum0);
        o1[px] = acc1 * frcp(sum1);
    }
}

// Fused rau: out = attnB(relu(attnA(relu(x)))) + x [+ extra]
// Tile 64x16 per workgroup, 256 threads.
// xs LDS: relu'd x, rows <-> gy = ty0-2+r (20), cols <-> gx = tx0-4+j (72)
// h1 LDS: relu'd attnA out, rows <-> gy = ty0-1+r (18), cols <-> gx = tx0-1+j (68 used)
template<int HAS_EXTRA>
__global__ __launch_bounds__(256) void rau_kernel(
    const float* __restrict__ x, const float* __restrict__ extra,
    float* __restrict__ out,
    const float* __restrict__ wq, const float* __restrict__ bq,
    const float* __restrict__ wk, const float* __restrict__ bk,
    const float* __restrict__ wv, const float* __restrict__ bv,
    const float* __restrict__ rh, const float* __restrict__ rw,
    int iA, int iB)
{
    __shared__ float xs[2][20][72];
    __shared__ float h1[2][18][72];

    int tid = threadIdx.x;
    int bid = blockIdx.x;            // 2048 blocks: 8 tx * 32 ty * 8 batch
    int tx0 = (bid & 7) * 64;
    int ty0 = ((bid >> 3) & 31) * 16;
    int b   = bid >> 8;

    AttnW PA = load_w(wq, bq, wk, bk, wv, bv, rh, rw, iA);
    AttnW PB = load_w(wq, bq, wk, bk, wv, bv, rh, rw, iB);

    // ---- load phase: 40 row-ch * 18 float4 slots = 720
    const float* xb = x + b * BSTRIDE;
    for (int slot = tid; slot < 720; slot += 256) {
        int rc = slot / 18;
        int c4 = slot - rc * 18;
        int ch = rc >= 20 ? 1 : 0;
        int r  = ch ? rc - 20 : rc;
        int gy = ty0 - 2 + r;
        int gx = tx0 - 4 + 4 * c4;
        float4 v = make_float4(0.f, 0.f, 0.f, 0.f);
        if (gy >= 0 && gy < H && gx >= 0 && gx + 3 < W)
            v = *reinterpret_cast<const float4*>(xb + ch * PLANE + gy * W + gx);
        v.x = reluf(v.x); v.y = reluf(v.y); v.z = reluf(v.z); v.w = reluf(v.w);
        *reinterpret_cast<float4*>(&xs[ch][r][4 * c4]) = v;
    }
    __syncthreads();

    // ---- phase 1: attnA over 18 rows x 17 strips (px gx = tx0-1+4*c1+j)
    for (int strip = tid; strip < 306; strip += 256) {
        int row = strip / 17;
        int c1  = strip - row * 17;
        float t0[3][6], t1[3][6];
#pragma unroll
        for (int r = 0; r < 3; ++r) {
            const float* p0 = &xs[0][row + r][4 * c1];
            const float* p1 = &xs[1][row + r][4 * c1];
            float4 a = *reinterpret_cast<const float4*>(p0);
            float4 bb = *reinterpret_cast<const float4*>(p0 + 4);
            t0[r][0]=a.z; t0[r][1]=a.w; t0[r][2]=bb.x; t0[r][3]=bb.y; t0[r][4]=bb.z; t0[r][5]=bb.w;
            float4 c = *reinterpret_cast<const float4*>(p1);
            float4 d = *reinterpret_cast<const float4*>(p1 + 4);
            t1[r][0]=c.z; t1[r][1]=c.w; t1[r][2]=d.x; t1[r][3]=d.y; t1[r][4]=d.z; t1[r][5]=d.w;
        }
        float o0[4], o1[4];
        attn_strip(t0, t1, PA, o0, o1);
        int gy = ty0 - 1 + row;
        int gxb = tx0 - 1 + 4 * c1;
        bool rowin = (gy >= 0) && (gy < H);
        float w0[4], w1[4];
#pragma unroll
        for (int j = 0; j < 4; ++j) {
            bool in = rowin && (gxb + j >= 0) && (gxb + j < W);
            w0[j] = in ? reluf(o0[j]) : 0.f;
            w1[j] = in ? reluf(o1[j]) : 0.f;
        }
        *reinterpret_cast<float4*>(&h1[0][row][4 * c1]) = make_float4(w0[0], w0[1], w0[2], w0[3]);
        *reinterpret_cast<float4*>(&h1[1][row][4 * c1]) = make_float4(w1[0], w1[1], w1[2], w1[3]);
    }
    __syncthreads();

    // ---- phase 2: attnB over 16 rows x 16 strips (px gx = tx0+4*c2+j)
    {
        int row = tid >> 4;
        int c2  = tid & 15;
        float t0[3][6], t1[3][6];
#pragma unroll
        for (int r = 0; r < 3; ++r) {
            const float* p0 = &h1[0][row + r][4 * c2];
            const float* p1 = &h1[1][row + r][4 * c2];
            float4 a = *reinterpret_cast<const float4*>(p0);
            float4 bb = *reinterpret_cast<const float4*>(p0 + 4);
            t0[r][0]=a.x; t0[r][1]=a.y; t0[r][2]=a.z; t0[r][3]=a.w; t0[r][4]=bb.x; t0[r][5]=bb.y;
            float4 c = *reinterpret_cast<const float4*>(p1);
            float4 d = *reinterpret_cast<const float4*>(p1 + 4);
            t1[r][0]=c.x; t1[r][1]=c.y; t1[r][2]=c.z; t1[r][3]=c.w; t1[r][4]=d.x; t1[r][5]=d.y;
        }
        float o0[4], o1[4];
        attn_strip(t0, t1, PB, o0, o1);

        int gy = ty0 + row, gx = tx0 + 4 * c2;
        int base0 = b * BSTRIDE + gy * W + gx;
        int base1 = base0 + PLANE;
        float4 rx0 = *reinterpret_cast<const float4*>(x + base0);
        float4 rx1 = *reinterpret_cast<const float4*>(x + base1);
        o0[0] += rx0.x; o0[1] += rx0.y; o0[2] += rx0.z; o0[3] += rx0.w;
        o1[0] += rx1.x; o1[1] += rx1.y; o1[2] += rx1.z; o1[3] += rx1.w;
        if (HAS_EXTRA) {
            float4 e0 = *reinterpret_cast<const float4*>(extra + base0);
            float4 e1 = *reinterpret_cast<const float4*>(extra + base1);
            o0[0] += e0.x; o0[1] += e0.y; o0[2] += e0.z; o0[3] += e0.w;
            o1[0] += e1.x; o1[1] += e1.y; o1[2] += e1.z; o1[3] += e1.w;
        }
        *reinterpret_cast<float4*>(out + base0) = make_float4(o0[0], o0[1], o0[2], o0[3]);
        *reinterpret_cast<float4*>(out + base1) = make_float4(o1[0], o1[1], o1[2], o1[3]);
    }
}

// reflect-pad 3x3 conv (2ch -> 1ch) + sigmoid, 4 px per thread
__global__ __launch_bounds__(256) void conv_sig4_kernel(
    const float* __restrict__ u,
    const float* __restrict__ cw, const float* __restrict__ cb,
    float* __restrict__ o)
{
    int s  = blockIdx.x * 256 + threadIdx.x;
    int x0 = (s & 127) * 4;
    int y  = (s >> 7) & 511;
    int b  = s >> 16;

    float w[18];
#pragma unroll
    for (int i = 0; i < 18; ++i) w[i] = cw[i];

    int yy[3];
#pragma unroll
    for (int i = 0; i < 3; ++i) {
        int t = y + i - 1;
        if (t < 0) t = -t;
        if (t > H - 1) t = 2 * (H - 1) - t;
        yy[i] = t;
    }
    int xl = x0 - 1; if (xl < 0) xl = 1;
    int xr = x0 + 4; if (xr > W - 1) xr = 2 * (W - 1) - xr;

    float acc[4] = { cb[0], cb[0], cb[0], cb[0] };
#pragma unroll
    for (int c = 0; c < 2; ++c) {
        const float* up = u + b * BSTRIDE + c * PLANE;
#pragma unroll
        for (int i = 0; i < 3; ++i) {
            const float* row = up + yy[i] * W;
            float4 a = *reinterpret_cast<const float4*>(row + x0);
            float t[6] = { row[xl], a.x, a.y, a.z, a.w, row[xr] };
#pragma unroll
            for (int j = 0; j < 3; ++j) {
                float wc = w[c * 9 + i * 3 + j];
#pragma unroll
                for (int px = 0; px < 4; ++px)
                    acc[px] = fmaf(t[px + j], wc, acc[px]);
            }
        }
    }
    float4 ov;
    ov.x = frcp(1.f + exp2f(-acc[0] * LOG2E));
    ov.y = frcp(1.f + exp2f(-acc[1] * LOG2E));
    ov.z = frcp(1.f + exp2f(-acc[2] * LOG2E));
    ov.w = frcp(1.f + exp2f(-acc[3] * LOG2E));
    *reinterpret_cast<float4*>(o + b * PLANE + y * W + x0) = ov;
}

// 2x bilinear upsample (linspace(0,511,1024) grid), 4 out px per thread
__global__ __launch_bounds__(256) void upsample4_kernel(
    const float* __restrict__ o, float* __restrict__ up)
{
    int p  = blockIdx.x * 256 + threadIdx.x;
    int b  = p >> 18;
    int y  = (p >> 8) & 1023;
    int x0 = (p & 255) * 4;

    const float scale = 511.0f / 1023.0f;
    float fy = y * scale;
    int y0 = (int)fy;
    float wy = fy - y0;
    int y1 = min(y0 + 1, H - 1);

    const float* ob = o + b * PLANE;
    const float* row0 = ob + y0 * W;
    const float* row1 = ob + y1 * W;

    float4 ov;
    float* ovp = &ov.x;
#pragma unroll
    for (int j = 0; j < 4; ++j) {
        float fx = (x0 + j) * scale;
        int xi = (int)fx;
        float wx = fx - xi;
        int xi1 = min(xi + 1, W - 1);
        float v00 = row0[xi], v01 = row0[xi1];
        float v10 = row1[xi], v11 = row1[xi1];
        float top = fmaf(v01 - v00, wx, v00);
        float bot = fmaf(v11 - v10, wx, v10);
        ovp[j] = fmaf(bot - top, wy, top);
    }
    *reinterpret_cast<float4*>(up + ((long)b << 20) + y * 1024 + x0) = ov;
}

extern "C" void kernel_launch(void* const* d_in, const int* in_sizes, int n_in,
                              void* d_out, int out_size, void* d_ws, size_t ws_size,
                              hipStream_t stream) {
    const float* in1 = (const float*)d_in[0];
    const float* in2 = (const float*)d_in[1];
    const float* wq  = (const float*)d_in[2];
    const float* bq  = (const float*)d_in[3];
    const float* wk  = (const float*)d_in[4];
    const float* bk  = (const float*)d_in[5];
    const float* wv  = (const float*)d_in[6];
    const float* bv  = (const float*)d_in[7];
    const float* rh  = (const float*)d_in[8];
    const float* rw  = (const float*)d_in[9];
    const float* cw  = (const float*)d_in[10];
    const float* cb  = (const float*)d_in[11];

    float* out = (float*)d_out;
    float* bufA = (float*)d_ws;        // r1
    float* bufB = out + 4194304;       // t  (overwritten only after conv reads it)
    float* bufC = out;                 // s  (clobbered by conv output, s dead by then)
    (void)ws_size; (void)out_size; (void)n_in; (void)in_sizes;

    dim3 blk(256);
    int gridR = 2048;               // 8 * 32 * 8 tiles
    int gridC = (NPIX / 4) / 256;   // 2048
    int gridU = (UPN / 4) / 256;    // 8192

    // r1 = rau(in1; params 0,1)
    rau_kernel<0><<<gridR, blk, 0, stream>>>(in1, nullptr, bufA,
        wq, bq, wk, bk, wv, bv, rh, rw, 0, 1);
    // s = rau(in2; params 2,3) + r1
    rau_kernel<1><<<gridR, blk, 0, stream>>>(in2, bufA, bufC,
        wq, bq, wk, bk, wv, bv, rh, rw, 2, 3);
    // t = rau(s; params 4,5)
    rau_kernel<0><<<gridR, blk, 0, stream>>>(bufC, nullptr, bufB,
        wq, bq, wk, bk, wv, bv, rh, rw, 4, 5);
    // o = sigmoid(conv3x3(reflect_pad(t)))
    conv_sig4_kernel<<<gridC, blk, 0, stream>>>(bufB, cw, cb, out);
    // up = bilinear2x(o)
    upsample4_kernel<<<gridU, blk, 0, stream>>>(out, out + NPIX);
}

// Round 4
// 142.887 us; speedup vs baseline: 1.2123x; 1.2123x over previous
//
#include <hip/hip_runtime.h>

constexpr int B = 8, H = 512, W = 512;
constexpr int PLANE = H * W;              // 262144
constexpr int BSTRIDE = 2 * PLANE;
constexpr int NPIX = B * PLANE;           // 2097152
constexpr int UPN = B * 1024 * 1024;      // 8388608
constexpr int PPITCH = 520;               // padded row pitch (x pad: 4 left, 4 right)
constexpr int PXOFF  = 4;
constexpr int PPLANE = H * PPITCH;        // 266240 floats per (b,ch) plane
constexpr int PBUF   = 16 * PPLANE;       // 4,259,840 floats per padded tensor
constexpr float LOG2E = 1.4426950408889634f;

__device__ __forceinline__ float reluf(float v) { return v > 0.f ? v : 0.f; }
__device__ __forceinline__ float frcp(float v) { return __builtin_amdgcn_rcpf(v); }

struct AttnW {
    float wq00, wq01, wq10, wq11, bq0, bq1;
    float wk00, wk01, wk10, wk11, bk0, bk1;
    float wv00, wv01, wv10, wv11, bv0, bv1;
    float rh0, rh1, rh2, rw0, rw1, rw2;
};

__device__ __forceinline__ AttnW load_w(
    const float* wq, const float* bq, const float* wk, const float* bk,
    const float* wv, const float* bv, const float* rh, const float* rw, int i)
{
    AttnW P;
    P.wq00 = wq[4*i]; P.wq01 = wq[4*i+1]; P.wq10 = wq[4*i+2]; P.wq11 = wq[4*i+3];
    P.bq0  = bq[2*i]; P.bq1  = bq[2*i+1];
    P.wk00 = wk[4*i]; P.wk01 = wk[4*i+1]; P.wk10 = wk[4*i+2]; P.wk11 = wk[4*i+3];
    P.bk0  = bk[2*i]; P.bk1  = bk[2*i+1];
    P.wv00 = wv[4*i]; P.wv01 = wv[4*i+1]; P.wv10 = wv[4*i+2]; P.wv11 = wv[4*i+3];
    P.bv0  = bv[2*i]; P.bv1  = bv[2*i+1];
    P.rh0 = rh[3*i]; P.rh1 = rh[3*i+1]; P.rh2 = rh[3*i+2];
    P.rw0 = rw[3*i]; P.rw1 = rw[3*i+1]; P.rw2 = rw[3*i+2];
    return P;
}

// 4-px attn strip. t0/t1: relu'd (and zero-masked) 3x6 neighborhoods per channel.
// px j uses t[r][j..j+2]; center = t[1][j+1].
__device__ __forceinline__ void attn_strip(
    const float (&t0)[3][6], const float (&t1)[3][6],
    const AttnW& P, float (&o0)[4], float (&o1)[4])
{
    float kb0[3][6], kb1[3][6], v0[3][6], v1[3][6];
#pragma unroll
    for (int r = 0; r < 3; ++r)
#pragma unroll
        for (int c = 0; c < 6; ++c) {
            float u0 = t0[r][c], u1 = t1[r][c];
            kb0[r][c] = fmaf(P.wk00, u0, fmaf(P.wk01, u1, P.bk0));
            kb1[r][c] = fmaf(P.wk10, u0, fmaf(P.wk11, u1, P.bk1));
            v0[r][c]  = fmaf(P.wv00, u0, fmaf(P.wv01, u1, P.bv0));
            v1[r][c]  = fmaf(P.wv10, u0, fmaf(P.wv11, u1, P.bv1));
        }
    float rhv[3] = {P.rh0, P.rh1, P.rh2};
    float rwv[3] = {P.rw0, P.rw1, P.rw2};
#pragma unroll
    for (int px = 0; px < 4; ++px) {
        float c0 = t0[1][px + 1], c1 = t1[1][px + 1];
        float q0 = fmaf(P.wq00, c0, fmaf(P.wq01, c1, P.bq0)) * LOG2E;
        float q1 = fmaf(P.wq10, c0, fmaf(P.wq11, c1, P.bq1)) * LOG2E;
        float qh[3] = {q0 * rhv[0], q0 * rhv[1], q0 * rhv[2]};  // ch0: rh by row
        float qw[3] = {q1 * rwv[0], q1 * rwv[1], q1 * rwv[2]};  // ch1: rw by col
        float s0[9], s1[9];
#pragma unroll
        for (int r = 0; r < 3; ++r)
#pragma unroll
            for (int d = 0; d < 3; ++d) {
                s0[r*3+d] = fmaf(q0, kb0[r][px+d], qh[r]);
                s1[r*3+d] = fmaf(q1, kb1[r][px+d], qw[d]);
            }
        // v_max3 trees
        float m0 = fmaxf(fmaxf(fmaxf(fmaxf(s0[0],s0[1]),s0[2]),
                               fmaxf(fmaxf(s0[3],s0[4]),s0[5])),
                         fmaxf(fmaxf(s0[6],s0[7]),s0[8]));
        float m1 = fmaxf(fmaxf(fmaxf(fmaxf(s1[0],s1[1]),s1[2]),
                               fmaxf(fmaxf(s1[3],s1[4]),s1[5])),
                         fmaxf(fmaxf(s1[6],s1[7]),s1[8]));
        float sum0 = 0.f, acc0 = 0.f, sum1 = 0.f, acc1 = 0.f;
#pragma unroll
        for (int r = 0; r < 3; ++r)
#pragma unroll
            for (int d = 0; d < 3; ++d) {
                int t = r*3+d;
                float e0 = exp2f(s0[t] - m0);
                float e1 = exp2f(s1[t] - m1);
                sum0 += e0; acc0 = fmaf(e0, v0[r][px+d], acc0);
                sum1 += e1; acc1 = fmaf(e1, v1[r][px+d], acc1);
            }
        o0[px] = acc0 * frcp(sum0);
        o1[px] = acc1 * frcp(sum1);
    }
}

// zero the x-pad columns of the two padded buffers (runs first, every launch)
__global__ __launch_bounds__(256) void padzero_kernel(float* __restrict__ A,
                                                      float* __restrict__ Bb)
{
    int id = blockIdx.x * 256 + threadIdx.x;   // 131072 = 2 bufs*16 planes*512 rows*8 cols
    int c     = id & 7;
    int row   = (id >> 3) & 511;
    int plane = (id >> 12) & 15;
    float* base = (id >> 16) ? Bb : A;
    int col = (c < 4) ? c : (c + 512);         // cols 0..3 and 516..519
    base[plane * PPLANE + row * PPITCH + col] = 0.f;
}

// First stage (batched): reads unpadded external input with bounds checks,
// writes attn output to a PADDED buffer. blocks [0,2048) -> set A, [2048,4096) -> set B.
__global__ __launch_bounds__(256) void attn_in_kernel(
    const float* __restrict__ xA, const float* __restrict__ xB,
    float* __restrict__ outA, float* __restrict__ outB,
    const float* __restrict__ wq, const float* __restrict__ bq,
    const float* __restrict__ wk, const float* __restrict__ bk,
    const float* __restrict__ wv, const float* __restrict__ bv,
    const float* __restrict__ rh, const float* __restrict__ rw,
    int piA, int piB)
{
    int bid = blockIdx.x;
    bool second = bid >= 2048;
    const float* x = second ? xB : xA;
    float* outp = second ? outB : outA;
    int pi = second ? piB : piA;

    int s  = (second ? bid - 2048 : bid) * 256 + threadIdx.x;
    int x0 = (s & 127) * 4;
    int y  = (s >> 7) & 511;
    int b  = s >> 16;

    AttnW P = load_w(wq, bq, wk, bk, wv, bv, rh, rw, pi);

    const float* xb = x + b * BSTRIDE;
    bool rowv[3] = { y > 0, true, y < H - 1 };
    int  yr[3]   = { y > 0 ? y - 1 : 0, y, y < H - 1 ? y + 1 : H - 1 };
    bool lv   = x0 > 0;
    bool rvld = x0 < W - 4;
    int  xl = lv ? x0 - 1 : 0;
    int  xr = rvld ? x0 + 4 : W - 1;

    float t0[3][6], t1[3][6];
#pragma unroll
    for (int r = 0; r < 3; ++r) {
        const float* p0 = xb + yr[r] * W;
        const float* p1 = p0 + PLANE;
        float4 a0 = *reinterpret_cast<const float4*>(p0 + x0);
        float4 a1 = *reinterpret_cast<const float4*>(p1 + x0);
        float u0[6] = { p0[xl], a0.x, a0.y, a0.z, a0.w, p0[xr] };
        float u1[6] = { p1[xl], a1.x, a1.y, a1.z, a1.w, p1[xr] };
        bool rv_ = rowv[r];
#pragma unroll
        for (int c = 0; c < 6; ++c) {
            bool ok = rv_ && (c > 0 || lv) && (c < 5 || rvld);
            t0[r][c] = ok ? reluf(u0[c]) : 0.f;
            t1[r][c] = ok ? reluf(u1[c]) : 0.f;
        }
    }

    float o0[4], o1[4];
    attn_strip(t0, t1, P, o0, o1);

    int ob = (b * 2) * PPLANE + y * PPITCH + x0 + PXOFF;
    *reinterpret_cast<float4*>(outp + ob)          = make_float4(o0[0], o0[1], o0[2], o0[3]);
    *reinterpret_cast<float4*>(outp + ob + PPLANE) = make_float4(o1[0], o1[1], o1[2], o1[3]);
}

// Interior stages: input is a PADDED buffer (x-pads are zero), so no x bounds
// logic at all; y check is wave-uniform. Output/residual layouts are runtime args.
template<int NRES>
__global__ __launch_bounds__(256) void attn_fast_kernel(
    const float* __restrict__ xp,
    float* __restrict__ outp, int oPlane, int oPitch, int oXoff,
    const float* __restrict__ res0, int aPlane, int aPitch, int aXoff,
    const float* __restrict__ res1, int cPlane, int cPitch, int cXoff,
    const float* __restrict__ wq, const float* __restrict__ bq,
    const float* __restrict__ wk, const float* __restrict__ bk,
    const float* __restrict__ wv, const float* __restrict__ bv,
    const float* __restrict__ rh, const float* __restrict__ rw, int pi)
{
    int s  = blockIdx.x * 256 + threadIdx.x;
    int x0 = (s & 127) * 4;
    int y  = (s >> 7) & 511;   // wave-uniform (128 strips per row)
    int b  = s >> 16;

    AttnW P = load_w(wq, bq, wk, bk, wv, bv, rh, rw, pi);

    const float* xb0 = xp + (b * 2) * PPLANE + x0 + PXOFF;
    float t0[3][6], t1[3][6];
#pragma unroll
    for (int r = 0; r < 3; ++r) {
        int gy = y - 1 + r;
        bool ok = (unsigned)gy < (unsigned)H;   // wave-uniform
        int gyc = ok ? gy : y;
        const float* p0 = xb0 + gyc * PPITCH;
        const float* p1 = p0 + PPLANE;
        float4 a0 = *reinterpret_cast<const float4*>(p0);
        float4 a1 = *reinterpret_cast<const float4*>(p1);
        float e0l = p0[-1], e0r = p0[4];
        float e1l = p1[-1], e1r = p1[4];
        if (ok) {
            t0[r][0]=reluf(e0l); t0[r][1]=reluf(a0.x); t0[r][2]=reluf(a0.y);
            t0[r][3]=reluf(a0.z); t0[r][4]=reluf(a0.w); t0[r][5]=reluf(e0r);
            t1[r][0]=reluf(e1l); t1[r][1]=reluf(a1.x); t1[r][2]=reluf(a1.y);
            t1[r][3]=reluf(a1.z); t1[r][4]=reluf(a1.w); t1[r][5]=reluf(e1r);
        } else {
#pragma unroll
            for (int c = 0; c < 6; ++c) { t0[r][c] = 0.f; t1[r][c] = 0.f; }
        }
    }

    float o0[4], o1[4];
    attn_strip(t0, t1, P, o0, o1);

    if (NRES >= 1) {
        int rb = (b * 2) * aPlane + y * aPitch + x0 + aXoff;
        float4 ra = *reinterpret_cast<const float4*>(res0 + rb);
        float4 rbv = *reinterpret_cast<const float4*>(res0 + rb + aPlane);
        o0[0]+=ra.x; o0[1]+=ra.y; o0[2]+=ra.z; o0[3]+=ra.w;
        o1[0]+=rbv.x; o1[1]+=rbv.y; o1[2]+=rbv.z; o1[3]+=rbv.w;
    }
    if (NRES >= 2) {
        int rb = (b * 2) * cPlane + y * cPitch + x0 + cXoff;
        float4 ra = *reinterpret_cast<const float4*>(res1 + rb);
        float4 rbv = *reinterpret_cast<const float4*>(res1 + rb + cPlane);
        o0[0]+=ra.x; o0[1]+=ra.y; o0[2]+=ra.z; o0[3]+=ra.w;
        o1[0]+=rbv.x; o1[1]+=rbv.y; o1[2]+=rbv.z; o1[3]+=rbv.w;
    }

    int ob = (b * 2) * oPlane + y * oPitch + x0 + oXoff;
    *reinterpret_cast<float4*>(outp + ob)          = make_float4(o0[0], o0[1], o0[2], o0[3]);
    *reinterpret_cast<float4*>(outp + ob + oPlane) = make_float4(o1[0], o1[1], o1[2], o1[3]);
}

// reflect-pad 3x3 conv (2ch -> 1ch) + sigmoid; input unpadded layout
__global__ __launch_bounds__(256) void conv_sig4_kernel(
    const float* __restrict__ u,
    const float* __restrict__ cw, const float* __restrict__ cb,
    float* __restrict__ o)
{
    int s  = blockIdx.x * 256 + threadIdx.x;
    int x0 = (s & 127) * 4;
    int y  = (s >> 7) & 511;
    int b  = s >> 16;

    float w[18];
#pragma unroll
    for (int i = 0; i < 18; ++i) w[i] = cw[i];

    int yy[3];
#pragma unroll
    for (int i = 0; i < 3; ++i) {
        int t = y + i - 1;
        if (t < 0) t = -t;
        if (t > H - 1) t = 2 * (H - 1) - t;
        yy[i] = t;
    }
    int xl = x0 - 1; if (xl < 0) xl = 1;
    int xr = x0 + 4; if (xr > W - 1) xr = 2 * (W - 1) - xr;

    float acc[4] = { cb[0], cb[0], cb[0], cb[0] };
#pragma unroll
    for (int c = 0; c < 2; ++c) {
        const float* up = u + b * BSTRIDE + c * PLANE;
#pragma unroll
        for (int i = 0; i < 3; ++i) {
            const float* row = up + yy[i] * W;
            float4 a = *reinterpret_cast<const float4*>(row + x0);
            float t[6] = { row[xl], a.x, a.y, a.z, a.w, row[xr] };
#pragma unroll
            for (int j = 0; j < 3; ++j) {
                float wc = w[c * 9 + i * 3 + j];
#pragma unroll
                for (int px = 0; px < 4; ++px)
                    acc[px] = fmaf(t[px + j], wc, acc[px]);
            }
        }
    }
    float4 ov;
    ov.x = frcp(1.f + exp2f(-acc[0] * LOG2E));
    ov.y = frcp(1.f + exp2f(-acc[1] * LOG2E));
    ov.z = frcp(1.f + exp2f(-acc[2] * LOG2E));
    ov.w = frcp(1.f + exp2f(-acc[3] * LOG2E));
    *reinterpret_cast<float4*>(o + b * PLANE + y * W + x0) = ov;
}

// 2x bilinear upsample (linspace(0,511,1024) grid), 4 out px per thread
__global__ __launch_bounds__(256) void upsample4_kernel(
    const float* __restrict__ o, float* __restrict__ up)
{
    int p  = blockIdx.x * 256 + threadIdx.x;
    int b  = p >> 18;
    int y  = (p >> 8) & 1023;
    int x0 = (p & 255) * 4;

    const float scale = 511.0f / 1023.0f;
    float fy = y * scale;
    int y0 = (int)fy;
    float wy = fy - y0;
    int y1 = min(y0 + 1, H - 1);

    const float* ob = o + b * PLANE;
    const float* row0 = ob + y0 * W;
    const float* row1 = ob + y1 * W;

    float4 ov;
    float* ovp = &ov.x;
#pragma unroll
    for (int j = 0; j < 4; ++j) {
        float fx = (x0 + j) * scale;
        int xi = (int)fx;
        float wx = fx - xi;
        int xi1 = min(xi + 1, W - 1);
        float v00 = row0[xi], v01 = row0[xi1];
        float v10 = row1[xi], v11 = row1[xi1];
        float top = fmaf(v01 - v00, wx, v00);
        float bot = fmaf(v11 - v10, wx, v10);
        ovp[j] = fmaf(bot - top, wy, top);
    }
    *reinterpret_cast<float4*>(up + ((long)b << 20) + y * 1024 + x0) = ov;
}

extern "C" void kernel_launch(void* const* d_in, const int* in_sizes, int n_in,
                              void* d_out, int out_size, void* d_ws, size_t ws_size,
                              hipStream_t stream) {
    const float* in1 = (const float*)d_in[0];
    const float* in2 = (const float*)d_in[1];
    const float* wq  = (const float*)d_in[2];
    const float* bq  = (const float*)d_in[3];
    const float* wk  = (const float*)d_in[4];
    const float* bk  = (const float*)d_in[5];
    const float* wv  = (const float*)d_in[6];
    const float* bv  = (const float*)d_in[7];
    const float* rh  = (const float*)d_in[8];
    const float* rw  = (const float*)d_in[9];
    const float* cw  = (const float*)d_in[10];
    const float* cb  = (const float*)d_in[11];

    float* out = (float*)d_out;
    // A, B: padded tensors aliased into d_out (each 4,259,840 floats = 17.04MB).
    // Final o/up writes only happen after s (A) and t5 (B) are dead.
    float* A  = out;              // padded
    float* Bb = out + PBUF;       // padded  (PBUF*2 = 8,519,680 <= 10,485,760)
    float* C  = (float*)d_ws;     // unpadded 4,194,304 floats (proven ws capacity)
    (void)ws_size; (void)out_size; (void)n_in; (void)in_sizes;

    dim3 blk(256);

    padzero_kernel<<<512, blk, 0, stream>>>(A, Bb);
    // K1 (batched): t1 = attn0(relu(in1)) -> A ; t3 = attn2(relu(in2)) -> B
    attn_in_kernel<<<4096, blk, 0, stream>>>(in1, in2, A, Bb,
        wq, bq, wk, bk, wv, bv, rh, rw, 0, 2);
    // K2: r1 = attn1(relu(t1)) + in1 -> C (unpadded)
    attn_fast_kernel<1><<<2048, blk, 0, stream>>>(A, C, PLANE, W, 0,
        in1, PLANE, W, 0, nullptr, 0, 0, 0,
        wq, bq, wk, bk, wv, bv, rh, rw, 1);
    // K3: s = attn3(relu(t3)) + in2 + r1 -> A (padded)
    attn_fast_kernel<2><<<2048, blk, 0, stream>>>(Bb, A, PPLANE, PPITCH, PXOFF,
        in2, PLANE, W, 0, C, PLANE, W, 0,
        wq, bq, wk, bk, wv, bv, rh, rw, 3);
    // K4: t5 = attn4(relu(s)) -> B (padded)
    attn_fast_kernel<0><<<2048, blk, 0, stream>>>(A, Bb, PPLANE, PPITCH, PXOFF,
        nullptr, 0, 0, 0, nullptr, 0, 0, 0,
        wq, bq, wk, bk, wv, bv, rh, rw, 4);
    // K5: u = attn5(relu(t5)) + s -> C (unpadded); residual s is PADDED
    attn_fast_kernel<1><<<2048, blk, 0, stream>>>(Bb, C, PLANE, W, 0,
        A, PPLANE, PPITCH, PXOFF, nullptr, 0, 0, 0,
        wq, bq, wk, bk, wv, bv, rh, rw, 5);
    // K6: o = sigmoid(conv3x3(reflect_pad(u))) -> out[0:2M]
    conv_sig4_kernel<<<2048, blk, 0, stream>>>(C, cw, cb, out);
    // K7: up = bilinear2x(o) -> out[2M:10.48M]
    upsample4_kernel<<<8192, blk, 0, stream>>>(out, out + NPIX);
}

// Round 5
// 119.893 us; speedup vs baseline: 1.4448x; 1.1918x over previous
//
#include <hip/hip_runtime.h>

#if __has_builtin(__builtin_amdgcn_exp2f)
#define EXP2F(x) __builtin_amdgcn_exp2f(x)
#else
#define EXP2F(x) exp2f(x)
#endif

constexpr int B = 8, H = 512, W = 512;
constexpr int PLANE = H * W;              // 262144
constexpr int BSTRIDE = 2 * PLANE;
constexpr int NPIX = B * PLANE;           // 2097152
constexpr int UPN = B * 1024 * 1024;      // 8388608
constexpr int PPITCH = 520;               // padded row pitch (4 left, 4 right)
constexpr int PXOFF  = 4;
constexpr int PPLANE = H * PPITCH;        // 266240
constexpr int PBUF   = 16 * PPLANE;       // 4,259,840 floats per padded tensor
constexpr float LOG2E = 1.4426950408889634f;

__device__ __forceinline__ float reluf(float v) { return v > 0.f ? v : 0.f; }
__device__ __forceinline__ float frcp(float v) { return __builtin_amdgcn_rcpf(v); }

// k-side constants pre-scaled by LOG2E; rh folded per-row into bkr0L.
struct AttnW {
    float wq00, wq01, wq10, wq11, bq0, bq1;
    float wk00L, wk01L, wk10L, wk11L, bk1L;
    float bkr0L[3];           // (bk0 + rh[r]) * LOG2E
    float rwL[3];             // rw[d] * LOG2E
    float wv00, wv01, wv10, wv11, bv0, bv1;
};

__device__ __forceinline__ AttnW load_w(
    const float* wq, const float* bq, const float* wk, const float* bk,
    const float* wv, const float* bv, const float* rh, const float* rw, int i)
{
    AttnW P;
    P.wq00 = wq[4*i]; P.wq01 = wq[4*i+1]; P.wq10 = wq[4*i+2]; P.wq11 = wq[4*i+3];
    P.bq0  = bq[2*i]; P.bq1  = bq[2*i+1];
    P.wk00L = wk[4*i]   * LOG2E; P.wk01L = wk[4*i+1] * LOG2E;
    P.wk10L = wk[4*i+2] * LOG2E; P.wk11L = wk[4*i+3] * LOG2E;
    P.bk1L  = bk[2*i+1] * LOG2E;
    float bk0 = bk[2*i];
#pragma unroll
    for (int r = 0; r < 3; ++r) P.bkr0L[r] = (bk0 + rh[3*i+r]) * LOG2E;
#pragma unroll
    for (int d = 0; d < 3; ++d) P.rwL[d] = rw[3*i+d] * LOG2E;
    P.wv00 = wv[4*i]; P.wv01 = wv[4*i+1]; P.wv10 = wv[4*i+2]; P.wv11 = wv[4*i+3];
    P.bv0  = bv[2*i]; P.bv1  = bv[2*i+1];
    return P;
}

// 4-px attn strip, channel-packed layout: t[row][col][ch] relu'd (0 outside image).
// ch0 score: q0 * kk0 (rh+bias+L folded per location); ch1: fma(q1, kk1, q1*rwL[d]).
__device__ __forceinline__ void attn_strip(
    const float (&t)[3][6][2], const AttnW& P, float (&o)[4][2])
{
    float kk[3][6][2], vv[3][6][2];
#pragma unroll
    for (int r = 0; r < 3; ++r)
#pragma unroll
        for (int c = 0; c < 6; ++c) {
            float u0 = t[r][c][0], u1 = t[r][c][1];
            kk[r][c][0] = fmaf(P.wk00L, u0, fmaf(P.wk01L, u1, P.bkr0L[r]));
            kk[r][c][1] = fmaf(P.wk10L, u0, fmaf(P.wk11L, u1, P.bk1L));
            vv[r][c][0] = fmaf(P.wv00, u0, fmaf(P.wv01, u1, P.bv0));
            vv[r][c][1] = fmaf(P.wv10, u0, fmaf(P.wv11, u1, P.bv1));
        }
#pragma unroll
    for (int px = 0; px < 4; ++px) {
        float c0 = t[1][px+1][0], c1 = t[1][px+1][1];
        float q0 = fmaf(P.wq00, c0, fmaf(P.wq01, c1, P.bq0));
        float q1 = fmaf(P.wq10, c0, fmaf(P.wq11, c1, P.bq1));
        float qw[3] = { q1 * P.rwL[0], q1 * P.rwL[1], q1 * P.rwL[2] };
        float s[9][2];
#pragma unroll
        for (int r = 0; r < 3; ++r)
#pragma unroll
            for (int d = 0; d < 3; ++d) {
                s[r*3+d][0] = q0 * kk[r][px+d][0];
                s[r*3+d][1] = fmaf(q1, kk[r][px+d][1], qw[d]);
            }
        float m0 = fmaxf(fmaxf(fmaxf(fmaxf(s[0][0],s[1][0]),s[2][0]),
                               fmaxf(fmaxf(s[3][0],s[4][0]),s[5][0])),
                         fmaxf(fmaxf(s[6][0],s[7][0]),s[8][0]));
        float m1 = fmaxf(fmaxf(fmaxf(fmaxf(s[0][1],s[1][1]),s[2][1]),
                               fmaxf(fmaxf(s[3][1],s[4][1]),s[5][1])),
                         fmaxf(fmaxf(s[6][1],s[7][1]),s[8][1]));
        float sum0 = 0.f, acc0 = 0.f, sum1 = 0.f, acc1 = 0.f;
#pragma unroll
        for (int r = 0; r < 3; ++r)
#pragma unroll
            for (int d = 0; d < 3; ++d) {
                int tp = r*3+d;
                float e0 = EXP2F(s[tp][0] - m0);
                float e1 = EXP2F(s[tp][1] - m1);
                sum0 += e0; sum1 += e1;
                acc0 = fmaf(e0, vv[r][px+d][0], acc0);
                acc1 = fmaf(e1, vv[r][px+d][1], acc1);
            }
        o[px][0] = acc0 * frcp(sum0);
        o[px][1] = acc1 * frcp(sum1);
    }
}

// zero the x-pad columns for this row (called by padded-buffer writers)
__device__ __forceinline__ void write_pads(float* outp, int b2, int y, int x0)
{
    float4 z = make_float4(0.f, 0.f, 0.f, 0.f);
    if (x0 == 0) {
        int pb = b2 * PPLANE + y * PPITCH;                 // cols 0..3
        *reinterpret_cast<float4*>(outp + pb)          = z;
        *reinterpret_cast<float4*>(outp + pb + PPLANE) = z;
    } else if (x0 == W - 4) {
        int pb = b2 * PPLANE + y * PPITCH + PXOFF + W;     // cols 516..519
        *reinterpret_cast<float4*>(outp + pb)          = z;
        *reinterpret_cast<float4*>(outp + pb + PPLANE) = z;
    }
}

// First stage (batched): unpadded external input, bounds-checked; writes PADDED out.
__global__ __launch_bounds__(256) void attn_in_kernel(
    const float* __restrict__ xA, const float* __restrict__ xB,
    float* __restrict__ outA, float* __restrict__ outB,
    const float* __restrict__ wq, const float* __restrict__ bq,
    const float* __restrict__ wk, const float* __restrict__ bk,
    const float* __restrict__ wv, const float* __restrict__ bv,
    const float* __restrict__ rh, const float* __restrict__ rw,
    int piA, int piB)
{
    int bid = blockIdx.x;
    bool second = bid >= 2048;
    const float* x = second ? xB : xA;
    float* outp = second ? outB : outA;
    int pi = second ? piB : piA;

    int s  = (second ? bid - 2048 : bid) * 256 + threadIdx.x;
    int x0 = (s & 127) * 4;
    int y  = (s >> 7) & 511;
    int b  = s >> 16;

    AttnW P = load_w(wq, bq, wk, bk, wv, bv, rh, rw, pi);

    const float* xb = x + b * BSTRIDE;
    bool rowv[3] = { y > 0, true, y < H - 1 };
    int  yr[3]   = { y > 0 ? y - 1 : 0, y, y < H - 1 ? y + 1 : H - 1 };
    bool lv   = x0 > 0;
    bool rvld = x0 < W - 4;
    int  xl = lv ? x0 - 1 : 0;
    int  xr = rvld ? x0 + 4 : W - 1;

    float t[3][6][2];
#pragma unroll
    for (int r = 0; r < 3; ++r) {
        const float* p0 = xb + yr[r] * W;
        const float* p1 = p0 + PLANE;
        float4 a0 = *reinterpret_cast<const float4*>(p0 + x0);
        float4 a1 = *reinterpret_cast<const float4*>(p1 + x0);
        float u0[6] = { p0[xl], a0.x, a0.y, a0.z, a0.w, p0[xr] };
        float u1[6] = { p1[xl], a1.x, a1.y, a1.z, a1.w, p1[xr] };
        bool rv_ = rowv[r];
#pragma unroll
        for (int c = 0; c < 6; ++c) {
            bool ok = rv_ && (c > 0 || lv) && (c < 5 || rvld);
            t[r][c][0] = ok ? reluf(u0[c]) : 0.f;
            t[r][c][1] = ok ? reluf(u1[c]) : 0.f;
        }
    }

    float o[4][2];
    attn_strip(t, P, o);

    int ob = (b * 2) * PPLANE + y * PPITCH + x0 + PXOFF;
    *reinterpret_cast<float4*>(outp + ob)          = make_float4(o[0][0], o[1][0], o[2][0], o[3][0]);
    *reinterpret_cast<float4*>(outp + ob + PPLANE) = make_float4(o[0][1], o[1][1], o[2][1], o[3][1]);
    write_pads(outp, b * 2, y, x0);
}

// Interior stages: PADDED input (x-pads zero) -> no x bounds logic; y check wave-uniform.
template<int NRES, bool PADOUT>
__global__ __launch_bounds__(256) void attn_fast_kernel(
    const float* __restrict__ xp,
    float* __restrict__ outp, int oPlane, int oPitch, int oXoff,
    const float* __restrict__ res0, int aPlane, int aPitch, int aXoff,
    const float* __restrict__ res1, int cPlane, int cPitch, int cXoff,
    const float* __restrict__ wq, const float* __restrict__ bq,
    const float* __restrict__ wk, const float* __restrict__ bk,
    const float* __restrict__ wv, const float* __restrict__ bv,
    const float* __restrict__ rh, const float* __restrict__ rw, int pi)
{
    int s  = blockIdx.x * 256 + threadIdx.x;
    int x0 = (s & 127) * 4;
    int y  = (s >> 7) & 511;   // wave-uniform
    int b  = s >> 16;

    AttnW P = load_w(wq, bq, wk, bk, wv, bv, rh, rw, pi);

    const float* xb0 = xp + (b * 2) * PPLANE + x0 + PXOFF;
    float t[3][6][2];
#pragma unroll
    for (int r = 0; r < 3; ++r) {
        int gy = y - 1 + r;
        bool ok = (unsigned)gy < (unsigned)H;   // wave-uniform
        int gyc = ok ? gy : y;
        const float* p0 = xb0 + gyc * PPITCH;
        const float* p1 = p0 + PPLANE;
        float4 a0 = *reinterpret_cast<const float4*>(p0);
        float4 a1 = *reinterpret_cast<const float4*>(p1);
        float e0l = p0[-1], e0r = p0[4];
        float e1l = p1[-1], e1r = p1[4];
        if (ok) {
            t[r][0][0]=reluf(e0l);  t[r][0][1]=reluf(e1l);
            t[r][1][0]=reluf(a0.x); t[r][1][1]=reluf(a1.x);
            t[r][2][0]=reluf(a0.y); t[r][2][1]=reluf(a1.y);
            t[r][3][0]=reluf(a0.z); t[r][3][1]=reluf(a1.z);
            t[r][4][0]=reluf(a0.w); t[r][4][1]=reluf(a1.w);
            t[r][5][0]=reluf(e0r);  t[r][5][1]=reluf(e1r);
        } else {
#pragma unroll
            for (int c = 0; c < 6; ++c) { t[r][c][0] = 0.f; t[r][c][1] = 0.f; }
        }
    }

    float o[4][2];
    attn_strip(t, P, o);

    if (NRES >= 1) {
        int rb = (b * 2) * aPlane + y * aPitch + x0 + aXoff;
        float4 ra = *reinterpret_cast<const float4*>(res0 + rb);
        float4 rbv = *reinterpret_cast<const float4*>(res0 + rb + aPlane);
        o[0][0]+=ra.x; o[1][0]+=ra.y; o[2][0]+=ra.z; o[3][0]+=ra.w;
        o[0][1]+=rbv.x; o[1][1]+=rbv.y; o[2][1]+=rbv.z; o[3][1]+=rbv.w;
    }
    if (NRES >= 2) {
        int rb = (b * 2) * cPlane + y * cPitch + x0 + cXoff;
        float4 ra = *reinterpret_cast<const float4*>(res1 + rb);
        float4 rbv = *reinterpret_cast<const float4*>(res1 + rb + cPlane);
        o[0][0]+=ra.x; o[1][0]+=ra.y; o[2][0]+=ra.z; o[3][0]+=ra.w;
        o[0][1]+=rbv.x; o[1][1]+=rbv.y; o[2][1]+=rbv.z; o[3][1]+=rbv.w;
    }

    int ob = (b * 2) * oPlane + y * oPitch + x0 + oXoff;
    *reinterpret_cast<float4*>(outp + ob)          = make_float4(o[0][0], o[1][0], o[2][0], o[3][0]);
    *reinterpret_cast<float4*>(outp + ob + oPlane) = make_float4(o[0][1], o[1][1], o[2][1], o[3][1]);
    if (PADOUT) write_pads(outp, b * 2, y, x0);
}

// reflect-pad 3x3 conv (2ch -> 1ch) + sigmoid; unpadded input
__global__ __launch_bounds__(256) void conv_sig4_kernel(
    const float* __restrict__ u,
    const float* __restrict__ cw, const float* __restrict__ cb,
    float* __restrict__ o)
{
    int s  = blockIdx.x * 256 + threadIdx.x;
    int x0 = (s & 127) * 4;
    int y  = (s >> 7) & 511;
    int b  = s >> 16;

    float w[18];
#pragma unroll
    for (int i = 0; i < 18; ++i) w[i] = cw[i];

    int yy[3];
#pragma unroll
    for (int i = 0; i < 3; ++i) {
        int t = y + i - 1;
        if (t < 0) t = -t;
        if (t > H - 1) t = 2 * (H - 1) - t;
        yy[i] = t;
    }
    int xl = x0 - 1; if (xl < 0) xl = 1;
    int xr = x0 + 4; if (xr > W - 1) xr = 2 * (W - 1) - xr;

    float acc[4] = { cb[0], cb[0], cb[0], cb[0] };
#pragma unroll
    for (int c = 0; c < 2; ++c) {
        const float* up = u + b * BSTRIDE + c * PLANE;
#pragma unroll
        for (int i = 0; i < 3; ++i) {
            const float* row = up + yy[i] * W;
            float4 a = *reinterpret_cast<const float4*>(row + x0);
            float t[6] = { row[xl], a.x, a.y, a.z, a.w, row[xr] };
#pragma unroll
            for (int j = 0; j < 3; ++j) {
                float wc = w[c * 9 + i * 3 + j];
#pragma unroll
                for (int px = 0; px < 4; ++px)
                    acc[px] = fmaf(t[px + j], wc, acc[px]);
            }
        }
    }
    float4 ov;
    ov.x = frcp(1.f + EXP2F(-acc[0] * LOG2E));
    ov.y = frcp(1.f + EXP2F(-acc[1] * LOG2E));
    ov.z = frcp(1.f + EXP2F(-acc[2] * LOG2E));
    ov.w = frcp(1.f + EXP2F(-acc[3] * LOG2E));
    *reinterpret_cast<float4*>(o + b * PLANE + y * W + x0) = ov;
}

// 2x bilinear upsample (linspace(0,511,1024) grid), 4 out px per thread
__global__ __launch_bounds__(256) void upsample4_kernel(
    const float* __restrict__ o, float* __restrict__ up)
{
    int p  = blockIdx.x * 256 + threadIdx.x;
    int b  = p >> 18;
    int y  = (p >> 8) & 1023;
    int x0 = (p & 255) * 4;

    const float scale = 511.0f / 1023.0f;
    float fy = y * scale;
    int y0 = (int)fy;
    float wy = fy - y0;
    int y1 = min(y0 + 1, H - 1);

    const float* ob = o + b * PLANE;
    const float* row0 = ob + y0 * W;
    const float* row1 = ob + y1 * W;

    float4 ov;
    float* ovp = &ov.x;
#pragma unroll
    for (int j = 0; j < 4; ++j) {
        float fx = (x0 + j) * scale;
        int xi = (int)fx;
        float wx = fx - xi;
        int xi1 = min(xi + 1, W - 1);
        float v00 = row0[xi], v01 = row0[xi1];
        float v10 = row1[xi], v11 = row1[xi1];
        float top = fmaf(v01 - v00, wx, v00);
        float bot = fmaf(v11 - v10, wx, v10);
        ovp[j] = fmaf(bot - top, wy, top);
    }
    *reinterpret_cast<float4*>(up + ((long)b << 20) + y * 1024 + x0) = ov;
}

extern "C" void kernel_launch(void* const* d_in, const int* in_sizes, int n_in,
                              void* d_out, int out_size, void* d_ws, size_t ws_size,
                              hipStream_t stream) {
    const float* in1 = (const float*)d_in[0];
    const float* in2 = (const float*)d_in[1];
    const float* wq  = (const float*)d_in[2];
    const float* bq  = (const float*)d_in[3];
    const float* wk  = (const float*)d_in[4];
    const float* bk  = (const float*)d_in[5];
    const float* wv  = (const float*)d_in[6];
    const float* bv  = (const float*)d_in[7];
    const float* rh  = (const float*)d_in[8];
    const float* rw  = (const float*)d_in[9];
    const float* cw  = (const float*)d_in[10];
    const float* cb  = (const float*)d_in[11];

    float* out = (float*)d_out;
    float* A  = out;              // padded tensor 0
    float* Bb = out + PBUF;       // padded tensor 1 (2*PBUF = 8,519,680 <= 10,485,760)
    float* C  = (float*)d_ws;     // unpadded scratch
    (void)ws_size; (void)out_size; (void)n_in; (void)in_sizes;

    dim3 blk(256);

    // K1 (batched): t1 = attn0(relu(in1)) -> A ; t3 = attn2(relu(in2)) -> B  (pads folded)
    attn_in_kernel<<<4096, blk, 0, stream>>>(in1, in2, A, Bb,
        wq, bq, wk, bk, wv, bv, rh, rw, 0, 2);
    // K2: r1 = attn1(relu(t1)) + in1 -> C
    attn_fast_kernel<1,false><<<2048, blk, 0, stream>>>(A, C, PLANE, W, 0,
        in1, PLANE, W, 0, nullptr, 0, 0, 0,
        wq, bq, wk, bk, wv, bv, rh, rw, 1);
    // K3: s = attn3(relu(t3)) + in2 + r1 -> A (padded, pads folded)
    attn_fast_kernel<2,true><<<2048, blk, 0, stream>>>(Bb, A, PPLANE, PPITCH, PXOFF,
        in2, PLANE, W, 0, C, PLANE, W, 0,
        wq, bq, wk, bk, wv, bv, rh, rw, 3);
    // K4: t5 = attn4(relu(s)) -> B (padded, pads folded)
    attn_fast_kernel<0,true><<<2048, blk, 0, stream>>>(A, Bb, PPLANE, PPITCH, PXOFF,
        nullptr, 0, 0, 0, nullptr, 0, 0, 0,
        wq, bq, wk, bk, wv, bv, rh, rw, 4);
    // K5: u = attn5(relu(t5)) + s -> C  (residual s is padded)
    attn_fast_kernel<1,false><<<2048, blk, 0, stream>>>(Bb, C, PLANE, W, 0,
        A, PPLANE, PPITCH, PXOFF, nullptr, 0, 0, 0,
        wq, bq, wk, bk, wv, bv, rh, rw, 5);
    // K6: o = sigmoid(conv3x3(reflect_pad(u))) -> out[0:2M]
    conv_sig4_kernel<<<2048, blk, 0, stream>>>(C, cw, cb, out);
    // K7: up = bilinear2x(o) -> out[2M:]
    upsample4_kernel<<<8192, blk, 0, stream>>>(out, out + NPIX);
}

// Round 6
// 115.737 us; speedup vs baseline: 1.4967x; 1.0359x over previous
//
#include <hip/hip_runtime.h>

#if __has_builtin(__builtin_amdgcn_exp2f)
#define EXP2F(x) __builtin_amdgcn_exp2f(x)
#else
#define EXP2F(x) exp2f(x)
#endif

typedef float v2f __attribute__((ext_vector_type(2)));

constexpr int B = 8, H = 512, W = 512;
constexpr int PLANE = H * W;              // 262144
constexpr int BSTRIDE = 2 * PLANE;
constexpr int NPIX = B * PLANE;           // 2097152
constexpr int UPN = B * 1024 * 1024;      // 8388608
constexpr int PPITCH = 520;               // padded row pitch (4 left, 4 right)
constexpr int PXOFF  = 4;
constexpr int PPLANE = H * PPITCH;        // 266240
constexpr int PBUF   = 16 * PPLANE;       // 4,259,840 floats per padded tensor
constexpr float LOG2E = 1.4426950408889634f;

__device__ __forceinline__ float reluf(float v) { return v > 0.f ? v : 0.f; }
__device__ __forceinline__ float frcp(float v) { return __builtin_amdgcn_rcpf(v); }
__device__ __forceinline__ v2f vfma(v2f a, v2f b, v2f c) { return __builtin_elementwise_fma(a, b, c); }
__device__ __forceinline__ v2f vmax2(v2f a, v2f b) { return __builtin_elementwise_max(a, b); }
__device__ __forceinline__ v2f bc(float x) { v2f r; r.x = x; r.y = x; return r; }

// channel-pair packed weights; k-side pre-scaled by LOG2E, rh folded per-row.
struct AttnW {
    v2f wq0, wq1, bq;          // q = fma(wq0, bc(c0), fma(wq1, bc(c1), bq))
    v2f wk0, wk1;              // * LOG2E
    v2f biasK[3];              // ( (bk0+rh[r])*L , bk1*L )
    float rwL[3];              // rw[d]*L  (ch1 additive)
    v2f wv0, wv1, bv;
};

__device__ __forceinline__ AttnW load_w(
    const float* wq, const float* bq, const float* wk, const float* bk,
    const float* wv, const float* bv, const float* rh, const float* rw, int i)
{
    AttnW P;
    P.wq0.x = wq[4*i];   P.wq0.y = wq[4*i+2];
    P.wq1.x = wq[4*i+1]; P.wq1.y = wq[4*i+3];
    P.bq.x  = bq[2*i];   P.bq.y  = bq[2*i+1];
    P.wk0.x = wk[4*i]   * LOG2E; P.wk0.y = wk[4*i+2] * LOG2E;
    P.wk1.x = wk[4*i+1] * LOG2E; P.wk1.y = wk[4*i+3] * LOG2E;
    float bk1L = bk[2*i+1] * LOG2E;
#pragma unroll
    for (int r = 0; r < 3; ++r) {
        P.biasK[r].x = (bk[2*i] + rh[3*i+r]) * LOG2E;
        P.biasK[r].y = bk1L;
    }
#pragma unroll
    for (int d = 0; d < 3; ++d) P.rwL[d] = rw[3*i+d] * LOG2E;
    P.wv0.x = wv[4*i];   P.wv0.y = wv[4*i+2];
    P.wv1.x = wv[4*i+1]; P.wv1.y = wv[4*i+3];
    P.bv.x  = bv[2*i];   P.bv.y  = bv[2*i+1];
    return P;
}

// 4-px attn strip, channels packed in v2f lanes. t[row][col] = (relu ch0, relu ch1),
// zero outside image. px j uses t[r][j..j+2]; center = t[1][j+1].
__device__ __forceinline__ void attn_strip(
    const v2f (&t)[3][6], const AttnW& P, v2f (&o)[4])
{
    v2f kk[3][6], vv[3][6];
#pragma unroll
    for (int r = 0; r < 3; ++r)
#pragma unroll
        for (int c = 0; c < 6; ++c) {
            v2f u0 = bc(t[r][c].x), u1 = bc(t[r][c].y);
            kk[r][c] = vfma(P.wk0, u0, vfma(P.wk1, u1, P.biasK[r]));
            vv[r][c] = vfma(P.wv0, u0, vfma(P.wv1, u1, P.bv));
        }
#pragma unroll
    for (int px = 0; px < 4; ++px) {
        v2f q = vfma(P.wq0, bc(t[1][px+1].x), vfma(P.wq1, bc(t[1][px+1].y), P.bq));
        v2f addv[3];
#pragma unroll
        for (int d = 0; d < 3; ++d) { addv[d].x = 0.f; addv[d].y = q.y * P.rwL[d]; }
        v2f s[9];
#pragma unroll
        for (int r = 0; r < 3; ++r)
#pragma unroll
            for (int d = 0; d < 3; ++d)
                s[r*3+d] = vfma(q, kk[r][px+d], addv[d]);
        v2f m = vmax2(vmax2(vmax2(vmax2(s[0], s[1]), vmax2(s[2], s[3])),
                            vmax2(vmax2(s[4], s[5]), vmax2(s[6], s[7]))), s[8]);
        v2f sum = bc(0.f), acc = bc(0.f);
#pragma unroll
        for (int r = 0; r < 3; ++r)
#pragma unroll
            for (int d = 0; d < 3; ++d) {
                v2f dd = s[r*3+d] - m;
                v2f e; e.x = EXP2F(dd.x); e.y = EXP2F(dd.y);
                sum += e;
                acc = vfma(e, vv[r][px+d], acc);
            }
        v2f rs; rs.x = frcp(sum.x); rs.y = frcp(sum.y);
        o[px] = acc * rs;
    }
}

// zero the x-pad columns for this row (called by padded-buffer writers)
__device__ __forceinline__ void write_pads(float* outp, int b2, int y, int x0)
{
    float4 z = make_float4(0.f, 0.f, 0.f, 0.f);
    if (x0 == 0) {
        int pb = b2 * PPLANE + y * PPITCH;                 // cols 0..3
        *reinterpret_cast<float4*>(outp + pb)          = z;
        *reinterpret_cast<float4*>(outp + pb + PPLANE) = z;
    } else if (x0 == W - 4) {
        int pb = b2 * PPLANE + y * PPITCH + PXOFF + W;     // cols 516..519
        *reinterpret_cast<float4*>(outp + pb)          = z;
        *reinterpret_cast<float4*>(outp + pb + PPLANE) = z;
    }
}

// First stage (batched): unpadded external input, bounds-checked; writes PADDED out.
__global__ __launch_bounds__(256) void attn_in_kernel(
    const float* __restrict__ xA, const float* __restrict__ xB,
    float* __restrict__ outA, float* __restrict__ outB,
    const float* __restrict__ wq, const float* __restrict__ bq,
    const float* __restrict__ wk, const float* __restrict__ bk,
    const float* __restrict__ wv, const float* __restrict__ bv,
    const float* __restrict__ rh, const float* __restrict__ rw,
    int piA, int piB)
{
    int bid = blockIdx.x;
    bool second = bid >= 2048;
    const float* x = second ? xB : xA;
    float* outp = second ? outB : outA;
    int pi = second ? piB : piA;

    int s  = (second ? bid - 2048 : bid) * 256 + threadIdx.x;
    int x0 = (s & 127) * 4;
    int y  = (s >> 7) & 511;
    int b  = s >> 16;

    AttnW P = load_w(wq, bq, wk, bk, wv, bv, rh, rw, pi);

    const float* xb = x + b * BSTRIDE;
    bool rowv[3] = { y > 0, true, y < H - 1 };
    int  yr[3]   = { y > 0 ? y - 1 : 0, y, y < H - 1 ? y + 1 : H - 1 };
    bool lv   = x0 > 0;
    bool rvld = x0 < W - 4;
    int  xl = lv ? x0 - 1 : 0;
    int  xr = rvld ? x0 + 4 : W - 1;

    v2f t[3][6];
#pragma unroll
    for (int r = 0; r < 3; ++r) {
        const float* p0 = xb + yr[r] * W;
        const float* p1 = p0 + PLANE;
        float4 a0 = *reinterpret_cast<const float4*>(p0 + x0);
        float4 a1 = *reinterpret_cast<const float4*>(p1 + x0);
        float u0[6] = { p0[xl], a0.x, a0.y, a0.z, a0.w, p0[xr] };
        float u1[6] = { p1[xl], a1.x, a1.y, a1.z, a1.w, p1[xr] };
        bool rv_ = rowv[r];
#pragma unroll
        for (int c = 0; c < 6; ++c) {
            bool ok = rv_ && (c > 0 || lv) && (c < 5 || rvld);
            t[r][c].x = ok ? reluf(u0[c]) : 0.f;
            t[r][c].y = ok ? reluf(u1[c]) : 0.f;
        }
    }

    v2f o[4];
    attn_strip(t, P, o);

    int ob = (b * 2) * PPLANE + y * PPITCH + x0 + PXOFF;
    *reinterpret_cast<float4*>(outp + ob)          = make_float4(o[0].x, o[1].x, o[2].x, o[3].x);
    *reinterpret_cast<float4*>(outp + ob + PPLANE) = make_float4(o[0].y, o[1].y, o[2].y, o[3].y);
    write_pads(outp, b * 2, y, x0);
}

// Interior stages: PADDED input (x-pads zero) -> no x bounds logic; y check wave-uniform.
template<int NRES, bool PADOUT>
__global__ __launch_bounds__(256) void attn_fast_kernel(
    const float* __restrict__ xp,
    float* __restrict__ outp, int oPlane, int oPitch, int oXoff,
    const float* __restrict__ res0, int aPlane, int aPitch, int aXoff,
    const float* __restrict__ res1, int cPlane, int cPitch, int cXoff,
    const float* __restrict__ wq, const float* __restrict__ bq,
    const float* __restrict__ wk, const float* __restrict__ bk,
    const float* __restrict__ wv, const float* __restrict__ bv,
    const float* __restrict__ rh, const float* __restrict__ rw, int pi)
{
    int s  = blockIdx.x * 256 + threadIdx.x;
    int x0 = (s & 127) * 4;
    int y  = (s >> 7) & 511;   // wave-uniform
    int b  = s >> 16;

    AttnW P = load_w(wq, bq, wk, bk, wv, bv, rh, rw, pi);

    const float* xb0 = xp + (b * 2) * PPLANE + x0 + PXOFF;
    v2f t[3][6];
#pragma unroll
    for (int r = 0; r < 3; ++r) {
        int gy = y - 1 + r;
        bool ok = (unsigned)gy < (unsigned)H;   // wave-uniform
        int gyc = ok ? gy : y;
        const float* p0 = xb0 + gyc * PPITCH;
        const float* p1 = p0 + PPLANE;
        float4 a0 = *reinterpret_cast<const float4*>(p0);
        float4 a1 = *reinterpret_cast<const float4*>(p1);
        float e0l = p0[-1], e0r = p0[4];
        float e1l = p1[-1], e1r = p1[4];
        if (ok) {
            t[r][0].x=reluf(e0l);  t[r][0].y=reluf(e1l);
            t[r][1].x=reluf(a0.x); t[r][1].y=reluf(a1.x);
            t[r][2].x=reluf(a0.y); t[r][2].y=reluf(a1.y);
            t[r][3].x=reluf(a0.z); t[r][3].y=reluf(a1.z);
            t[r][4].x=reluf(a0.w); t[r][4].y=reluf(a1.w);
            t[r][5].x=reluf(e0r);  t[r][5].y=reluf(e1r);
        } else {
#pragma unroll
            for (int c = 0; c < 6; ++c) { t[r][c].x = 0.f; t[r][c].y = 0.f; }
        }
    }

    v2f o[4];
    attn_strip(t, P, o);

    if (NRES >= 1) {
        int rb = (b * 2) * aPlane + y * aPitch + x0 + aXoff;
        float4 ra = *reinterpret_cast<const float4*>(res0 + rb);
        float4 rbv = *reinterpret_cast<const float4*>(res0 + rb + aPlane);
        o[0].x+=ra.x; o[1].x+=ra.y; o[2].x+=ra.z; o[3].x+=ra.w;
        o[0].y+=rbv.x; o[1].y+=rbv.y; o[2].y+=rbv.z; o[3].y+=rbv.w;
    }
    if (NRES >= 2) {
        int rb = (b * 2) * cPlane + y * cPitch + x0 + cXoff;
        float4 ra = *reinterpret_cast<const float4*>(res1 + rb);
        float4 rbv = *reinterpret_cast<const float4*>(res1 + rb + cPlane);
        o[0].x+=ra.x; o[1].x+=ra.y; o[2].x+=ra.z; o[3].x+=ra.w;
        o[0].y+=rbv.x; o[1].y+=rbv.y; o[2].y+=rbv.z; o[3].y+=rbv.w;
    }

    int ob = (b * 2) * oPlane + y * oPitch + x0 + oXoff;
    *reinterpret_cast<float4*>(outp + ob)          = make_float4(o[0].x, o[1].x, o[2].x, o[3].x);
    *reinterpret_cast<float4*>(outp + ob + oPlane) = make_float4(o[0].y, o[1].y, o[2].y, o[3].y);
    if (PADOUT) write_pads(outp, b * 2, y, x0);
}

// reflect-pad 3x3 conv (2ch -> 1ch) + sigmoid; unpadded input
__global__ __launch_bounds__(256) void conv_sig4_kernel(
    const float* __restrict__ u,
    const float* __restrict__ cw, const float* __restrict__ cb,
    float* __restrict__ o)
{
    int s  = blockIdx.x * 256 + threadIdx.x;
    int x0 = (s & 127) * 4;
    int y  = (s >> 7) & 511;
    int b  = s >> 16;

    float w[18];
#pragma unroll
    for (int i = 0; i < 18; ++i) w[i] = cw[i];

    int yy[3];
#pragma unroll
    for (int i = 0; i < 3; ++i) {
        int t = y + i - 1;
        if (t < 0) t = -t;
        if (t > H - 1) t = 2 * (H - 1) - t;
        yy[i] = t;
    }
    int xl = x0 - 1; if (xl < 0) xl = 1;
    int xr = x0 + 4; if (xr > W - 1) xr = 2 * (W - 1) - xr;

    float acc[4] = { cb[0], cb[0], cb[0], cb[0] };
#pragma unroll
    for (int c = 0; c < 2; ++c) {
        const float* up = u + b * BSTRIDE + c * PLANE;
#pragma unroll
        for (int i = 0; i < 3; ++i) {
            const float* row = up + yy[i] * W;
            float4 a = *reinterpret_cast<const float4*>(row + x0);
            float t[6] = { row[xl], a.x, a.y, a.z, a.w, row[xr] };
#pragma unroll
            for (int j = 0; j < 3; ++j) {
                float wc = w[c * 9 + i * 3 + j];
#pragma unroll
                for (int px = 0; px < 4; ++px)
                    acc[px] = fmaf(t[px + j], wc, acc[px]);
            }
        }
    }
    float4 ov;
    ov.x = frcp(1.f + EXP2F(-acc[0] * LOG2E));
    ov.y = frcp(1.f + EXP2F(-acc[1] * LOG2E));
    ov.z = frcp(1.f + EXP2F(-acc[2] * LOG2E));
    ov.w = frcp(1.f + EXP2F(-acc[3] * LOG2E));
    *reinterpret_cast<float4*>(o + b * PLANE + y * W + x0) = ov;
}

// 2x bilinear upsample (linspace(0,511,1024) grid), 4 out px per thread
__global__ __launch_bounds__(256) void upsample4_kernel(
    const float* __restrict__ o, float* __restrict__ up)
{
    int p  = blockIdx.x * 256 + threadIdx.x;
    int b  = p >> 18;
    int y  = (p >> 8) & 1023;
    int x0 = (p & 255) * 4;

    const float scale = 511.0f / 1023.0f;
    float fy = y * scale;
    int y0 = (int)fy;
    float wy = fy - y0;
    int y1 = min(y0 + 1, H - 1);

    const float* ob = o + b * PLANE;
    const float* row0 = ob + y0 * W;
    const float* row1 = ob + y1 * W;

    float4 ov;
    float* ovp = &ov.x;
#pragma unroll
    for (int j = 0; j < 4; ++j) {
        float fx = (x0 + j) * scale;
        int xi = (int)fx;
        float wx = fx - xi;
        int xi1 = min(xi + 1, W - 1);
        float v00 = row0[xi], v01 = row0[xi1];
        float v10 = row1[xi], v11 = row1[xi1];
        float top = fmaf(v01 - v00, wx, v00);
        float bot = fmaf(v11 - v10, wx, v10);
        ovp[j] = fmaf(bot - top, wy, top);
    }
    *reinterpret_cast<float4*>(up + ((long)b << 20) + y * 1024 + x0) = ov;
}

extern "C" void kernel_launch(void* const* d_in, const int* in_sizes, int n_in,
                              void* d_out, int out_size, void* d_ws, size_t ws_size,
                              hipStream_t stream) {
    const float* in1 = (const float*)d_in[0];
    const float* in2 = (const float*)d_in[1];
    const float* wq  = (const float*)d_in[2];
    const float* bq  = (const float*)d_in[3];
    const float* wk  = (const float*)d_in[4];
    const float* bk  = (const float*)d_in[5];
    const float* wv  = (const float*)d_in[6];
    const float* bv  = (const float*)d_in[7];
    const float* rh  = (const float*)d_in[8];
    const float* rw  = (const float*)d_in[9];
    const float* cw  = (const float*)d_in[10];
    const float* cb  = (const float*)d_in[11];

    float* out = (float*)d_out;
    float* A  = out;              // padded tensor 0
    float* Bb = out + PBUF;       // padded tensor 1 (2*PBUF = 8,519,680 <= 10,485,760)
    float* C  = (float*)d_ws;     // unpadded scratch
    (void)ws_size; (void)out_size; (void)n_in; (void)in_sizes;

    dim3 blk(256);

    // K1 (batched): t1 = attn0(relu(in1)) -> A ; t3 = attn2(relu(in2)) -> B  (pads folded)
    attn_in_kernel<<<4096, blk, 0, stream>>>(in1, in2, A, Bb,
        wq, bq, wk, bk, wv, bv, rh, rw, 0, 2);
    // K2: r1 = attn1(relu(t1)) + in1 -> C
    attn_fast_kernel<1,false><<<2048, blk, 0, stream>>>(A, C, PLANE, W, 0,
        in1, PLANE, W, 0, nullptr, 0, 0, 0,
        wq, bq, wk, bk, wv, bv, rh, rw, 1);
    // K3: s = attn3(relu(t3)) + in2 + r1 -> A (padded, pads folded)
    attn_fast_kernel<2,true><<<2048, blk, 0, stream>>>(Bb, A, PPLANE, PPITCH, PXOFF,
        in2, PLANE, W, 0, C, PLANE, W, 0,
        wq, bq, wk, bk, wv, bv, rh, rw, 3);
    // K4: t5 = attn4(relu(s)) -> B (padded, pads folded)
    attn_fast_kernel<0,true><<<2048, blk, 0, stream>>>(A, Bb, PPLANE, PPITCH, PXOFF,
        nullptr, 0, 0, 0, nullptr, 0, 0, 0,
        wq, bq, wk, bk, wv, bv, rh, rw, 4);
    // K5: u = attn5(relu(t5)) + s -> C  (residual s is padded)
    attn_fast_kernel<1,false><<<2048, blk, 0, stream>>>(Bb, C, PLANE, W, 0,
        A, PPLANE, PPITCH, PXOFF, nullptr, 0, 0, 0,
        wq, bq, wk, bk, wv, bv, rh, rw, 5);
    // K6: o = sigmoid(conv3x3(reflect_pad(u))) -> out[0:2M]
    conv_sig4_kernel<<<2048, blk, 0, stream>>>(C, cw, cb, out);
    // K7: up = bilinear2x(o) -> out[2M:]
    upsample4_kernel<<<8192, blk, 0, stream>>>(out, out + NPIX);
}